// Round 1
// baseline (2679.193 us; speedup 1.0000x reference)
//
#include <hip/hip_runtime.h>

// ---------------------------------------------------------------------------
// MoleRec pipeline on gfx950.
// Structure:
//   prep: transpose+bf16 GIN MLP weights; detect mask byte-layout
//   per graph (sub, mol): embed -> 4x(edge_msg -> gin_mlp[MFMA]) -> mean pool
//   SAB on sub (492x128), mol_emb = avgproj @ mol_pool
//   masked softmax attention -> weighted agg -> score head -> sigmoid
// ---------------------------------------------------------------------------

typedef short short8 __attribute__((ext_vector_type(8)));
typedef float f32x4 __attribute__((ext_vector_type(4)));
typedef unsigned short us4 __attribute__((ext_vector_type(4)));

#define BN_RSQ 0.9999950000374997f   // 1/sqrt(1+1e-5)  (BatchNorm eval, var=1)
#define LN_EPS 1e-5f
#define NEGBIG -4294967296.0f        // -(1<<32), matches reference mask fill

__device__ __forceinline__ unsigned short f2bf(float x) {
  union { float f; unsigned int u; } v; v.f = x;
  unsigned int r = v.u + 0x7fffu + ((v.u >> 16) & 1u);   // RNE
  return (unsigned short)(r >> 16);
}

// ---------------- weight prep: fp32 [K][N] -> bf16 [N][K] ------------------
__global__ void prep_weights(const float* __restrict__ w1, const float* __restrict__ w2,
                             unsigned short* __restrict__ w1t, unsigned short* __restrict__ w2t) {
  int i = blockIdx.x * 256 + threadIdx.x;
  if (i >= 262144) return;
  int gl = i >> 15;
  // w1: [2][4][128][256] -> w1t[gl][n=256][k=128]
  int k1 = (i >> 8) & 127, c1 = i & 255;
  w1t[(gl << 15) + c1 * 128 + k1] = f2bf(w1[i]);
  // w2: [2][4][256][128] -> w2t[gl][n=128][k=256]
  int k2 = (i >> 7) & 255, c2 = i & 127;
  w2t[(gl << 15) + c2 * 256 + k2] = f2bf(w2[i]);
}

// ---------------- mask layout detection ------------------------------------
// flags[0]: nonzero byte seen at pos%4==0 ; flags[1]: nonzero byte at pos%4!=0
// int32 0/1 -> (1,0) ; uint8 -> (1,1) ; float32 0/1.0 -> (0,1)
__global__ void mask_detect(const unsigned char* __restrict__ m, int* __restrict__ flags, int nbytes) {
  int i = blockIdx.x * 256 + threadIdx.x;
  if (i < nbytes && m[i]) {
    if ((i & 3) == 0) atomicOr(flags, 1);
    else atomicOr(flags + 1, 1);
  }
}

// ---------------- node embedding (also zeroes agg) --------------------------
__global__ void embed_nodes(const int* __restrict__ x, const float* __restrict__ table,
                            float* __restrict__ h, float* __restrict__ agg, int N) {
  int i = blockIdx.x * 256 + threadIdx.x;
  if (i >= N * 128) return;
  int n = i >> 7, c = i & 127;
  float s = 0.f;
#pragma unroll
  for (int f = 0; f < 9; f++) {
    int v = x[n * 9 + f];
    s += table[(f * 64 + v) * 128 + c];
  }
  h[i] = s;
  agg[i] = 0.f;
}

// ---------------- edge messages: relu(h[src]+bond_emb) scattered to tgt -----
__global__ void edge_msg(const int* __restrict__ ei, const int* __restrict__ attr,
                         const float* __restrict__ bt, const float* __restrict__ h,
                         float* __restrict__ agg, int E) {
  int i = blockIdx.x * 256 + threadIdx.x;
  if (i >= E * 128) return;
  int e = i >> 7, c = i & 127;
  int tgt = ei[e], src = ei[E + e];
  float v = h[src * 128 + c];
  v += bt[(0 * 64 + attr[e * 3 + 0]) * 128 + c];
  v += bt[(1 * 64 + attr[e * 3 + 1]) * 128 + c];
  v += bt[(2 * 64 + attr[e * 3 + 2]) * 128 + c];
  v = fmaxf(v, 0.f);
  atomicAdd(&agg[tgt * 128 + c], v);
}

// ---------------- fused GIN MLP: h = bn2(relu(bn1(z@w1+b1))@w2+b2) ---------
// z = (1+eps)*h + agg computed on the fly; bf16 MFMA 16x16x32; in-place h.
// Also zeroes agg for the next layer.
__global__ __launch_bounds__(256) void gin_mlp(
    float* __restrict__ h, float* __restrict__ agg, const float* __restrict__ eps_p,
    const unsigned short* __restrict__ w1t, const float* __restrict__ b1,
    const float* __restrict__ g1, const float* __restrict__ be1,
    const unsigned short* __restrict__ w2t, const float* __restrict__ b2,
    const float* __restrict__ g2, const float* __restrict__ be2,
    int N, int do_relu) {
  __shared__ unsigned short zs[64][136];    // 64x128 bf16, +8 pad
  __shared__ unsigned short z1s[64][264];   // 64x256 bf16, +8 pad
  int t = threadIdx.x;
  int r0 = blockIdx.x * 64;
  float eps1 = 1.0f + *eps_p;
  // Phase A: stage z tile in LDS (bf16), zero agg behind us
  for (int i = t; i < 2048; i += 256) {
    int r = i >> 5;
    int c4 = (i & 31) << 2;
    int n = r0 + r;
    us4 o;
    if (n < N) {
      float4 hv = *(const float4*)(h + n * 128 + c4);
      float4 av = *(const float4*)(agg + n * 128 + c4);
      o.x = f2bf(fmaf(eps1, hv.x, av.x));
      o.y = f2bf(fmaf(eps1, hv.y, av.y));
      o.z = f2bf(fmaf(eps1, hv.z, av.z));
      o.w = f2bf(fmaf(eps1, hv.w, av.w));
      *(float4*)(agg + n * 128 + c4) = make_float4(0.f, 0.f, 0.f, 0.f);
    } else {
      o.x = 0; o.y = 0; o.z = 0; o.w = 0;
    }
    *(us4*)&zs[r][c4] = o;
  }
  __syncthreads();
  int lane = t & 63, wave = t >> 6;
  int quad = lane >> 4, l16 = lane & 15;
  // Phase B: z1[64x256] = relu(bn1(z @ w1 + b1)); wave handles 64 cols
  {
    short8 bw[4][4];
    int cb = wave * 64;
#pragma unroll
    for (int nt = 0; nt < 4; nt++) {
      const unsigned short* p = w1t + (cb + nt * 16 + l16) * 128 + quad * 8;
#pragma unroll
      for (int kc = 0; kc < 4; kc++) bw[nt][kc] = *(const short8*)(p + kc * 32);
    }
#pragma unroll
    for (int mt = 0; mt < 4; mt++) {
      short8 af[4];
#pragma unroll
      for (int kc = 0; kc < 4; kc++)
        af[kc] = *(const short8*)&zs[mt * 16 + l16][kc * 32 + quad * 8];
#pragma unroll
      for (int nt = 0; nt < 4; nt++) {
        f32x4 acc = {0.f, 0.f, 0.f, 0.f};
#pragma unroll
        for (int kc = 0; kc < 4; kc++)
          acc = __builtin_amdgcn_mfma_f32_16x16x32_bf16(af[kc], bw[nt][kc], acc, 0, 0, 0);
        int c = cb + nt * 16 + l16;
        float sc = g1[c] * BN_RSQ, sh = be1[c], bb = b1[c];
#pragma unroll
        for (int reg = 0; reg < 4; reg++) {
          int r = mt * 16 + quad * 4 + reg;
          float y = (acc[reg] + bb) * sc + sh;
          z1s[r][c] = f2bf(fmaxf(y, 0.f));
        }
      }
    }
  }
  __syncthreads();
  // Phase C: h = bn2(z1 @ w2 + b2) (+relu); wave handles 32 cols
  {
    short8 bw[2][8];
    int cb = wave * 32;
#pragma unroll
    for (int nt = 0; nt < 2; nt++) {
      const unsigned short* p = w2t + (cb + nt * 16 + l16) * 256 + quad * 8;
#pragma unroll
      for (int kc = 0; kc < 8; kc++) bw[nt][kc] = *(const short8*)(p + kc * 32);
    }
#pragma unroll
    for (int mt = 0; mt < 4; mt++) {
      short8 af[8];
#pragma unroll
      for (int kc = 0; kc < 8; kc++)
        af[kc] = *(const short8*)&z1s[mt * 16 + l16][kc * 32 + quad * 8];
#pragma unroll
      for (int nt = 0; nt < 2; nt++) {
        f32x4 acc = {0.f, 0.f, 0.f, 0.f};
#pragma unroll
        for (int kc = 0; kc < 8; kc++)
          acc = __builtin_amdgcn_mfma_f32_16x16x32_bf16(af[kc], bw[nt][kc], acc, 0, 0, 0);
        int c = cb + nt * 16 + l16;
        float sc = g2[c] * BN_RSQ, sh = be2[c], bb = b2[c];
#pragma unroll
        for (int reg = 0; reg < 4; reg++) {
          int n = r0 + mt * 16 + quad * 4 + reg;
          if (n < N) {
            float y = (acc[reg] + bb) * sc + sh;
            if (do_relu) y = fmaxf(y, 0.f);
            h[n * 128 + c] = y;
          }
        }
      }
    }
  }
}

// ---------------- mean pooling ---------------------------------------------
__global__ void pool_add(const float* __restrict__ h, const int* __restrict__ batch,
                         float* __restrict__ pooled, float* __restrict__ cnt, int N) {
  int i = blockIdx.x * 256 + threadIdx.x;
  if (i >= N * 128) return;
  int n = i >> 7, c = i & 127;
  int b = batch[n];
  atomicAdd(&pooled[b * 128 + c], h[i]);
  if (c == 0) atomicAdd(&cnt[b], 1.0f);
}

__global__ void pool_div(float* __restrict__ pooled, const float* __restrict__ cnt, int total) {
  int i = blockIdx.x * 256 + threadIdx.x;
  if (i >= total) return;
  pooled[i] = pooled[i] / (cnt[i >> 7] + 1e-9f);
}

// ---------------- small generic GEMM: C = A[MxK] @ W[KxN] + bias -----------
__global__ void gemm_small(const float* __restrict__ A, const float* __restrict__ W,
                           const float* __restrict__ bias, float* __restrict__ C,
                           int M, int N, int K) {
  int i = blockIdx.x * 256 + threadIdx.x;
  if (i >= M * N) return;
  int r = i / N, c = i - r * N;
  float acc = bias ? bias[c] : 0.f;
  const float* a = A + (size_t)r * K;
  for (int k = 0; k < K; k++) acc = fmaf(a[k], W[(size_t)k * N + c], acc);
  C[i] = acc;
}

// ---------------- SAB attention: O = Qs + softmax(QsKs^T/8) Vs -------------
__global__ __launch_bounds__(256) void sab_attn(const float* __restrict__ Q, const float* __restrict__ K,
                                                const float* __restrict__ V, float* __restrict__ O, int S) {
  int q = blockIdx.x, hd = blockIdx.y;
  int t = threadIdx.x;
  __shared__ float sc[512];
  __shared__ float red[8];
  __shared__ float pacc[4][64];
  const float* qrow = Q + q * 128 + hd * 64;
  for (int k = t; k < 512; k += 256) {
    float d = -1e30f;
    if (k < S) {
      const float* krow = K + k * 128 + hd * 64;
      d = 0.f;
#pragma unroll
      for (int j = 0; j < 64; j += 4) {
        float4 a = *(const float4*)(qrow + j);
        float4 b = *(const float4*)(krow + j);
        d += a.x * b.x + a.y * b.y + a.z * b.z + a.w * b.w;
      }
      d *= 0.125f;   // 1/sqrt(64)
    }
    sc[k] = d;
  }
  __syncthreads();
  float m = fmaxf(sc[t], sc[t + 256]);
  for (int off = 32; off; off >>= 1) m = fmaxf(m, __shfl_down(m, off));
  if ((t & 63) == 0) red[t >> 6] = m;
  __syncthreads();
  m = fmaxf(fmaxf(red[0], red[1]), fmaxf(red[2], red[3]));
  float p0 = __expf(sc[t] - m), p1 = __expf(sc[t + 256] - m);
  sc[t] = p0; sc[t + 256] = p1;
  float s = p0 + p1;
  for (int off = 32; off; off >>= 1) s += __shfl_down(s, off);
  if ((t & 63) == 0) red[4 + (t >> 6)] = s;
  __syncthreads();
  float inv = 1.f / (red[4] + red[5] + red[6] + red[7]);
  int d = t & 63, part = t >> 6;
  float acc = 0.f;
  for (int k = part; k < S; k += 4) acc += sc[k] * V[k * 128 + hd * 64 + d];
  pacc[part][d] = acc;
  __syncthreads();
  if (part == 0) {
    float o = (pacc[0][d] + pacc[1][d] + pacc[2][d] + pacc[3][d]) * inv;
    O[q * 128 + hd * 64 + d] = qrow[d] + o;
  }
}

// ---------------- row LayerNorm over 128 ------------------------------------
__global__ __launch_bounds__(128) void ln_rows(const float* __restrict__ in, float* __restrict__ out,
                                               const float* __restrict__ g, const float* __restrict__ b) {
  int r = blockIdx.x, t = threadIdx.x;
  __shared__ float red[4];
  float x = in[r * 128 + t];
  float s = x;
  for (int off = 32; off; off >>= 1) s += __shfl_down(s, off);
  if ((t & 63) == 0) red[t >> 6] = s;
  __syncthreads();
  float mu = (red[0] + red[1]) * (1.f / 128.f);
  float dd = x - mu;
  float v = dd * dd;
  for (int off = 32; off; off >>= 1) v += __shfl_down(v, off);
  if ((t & 63) == 0) red[2 + (t >> 6)] = v;
  __syncthreads();
  float var = (red[2] + red[3]) * (1.f / 128.f);
  out[r * 128 + t] = g[t] * dd * rsqrtf(var + LN_EPS) + b[t];
}

// ---------------- masked softmax attn: attn[d,s] ----------------------------
__global__ __launch_bounds__(256) void agg_attn(const float* __restrict__ Q, const float* __restrict__ Kt,
                                                const void* __restrict__ mask, const int* __restrict__ flags,
                                                float* __restrict__ attn, int D, int S) {
  int d = blockIdx.x, t = threadIdx.x;
  __shared__ float sc[512];
  __shared__ float red[8];
  int layout = (flags[1] == 0) ? 0 : (flags[0] ? 1 : 2);
  const float* qrow = Q + d * 128;
  for (int s = t; s < 512; s += 256) {
    float v = NEGBIG;
    if (s < S) {
      int mi = d * S + s;
      bool msk;
      if (layout == 0)      msk = ((const int*)mask)[mi] != 0;
      else if (layout == 1) msk = ((const unsigned char*)mask)[mi] != 0;
      else                  msk = ((const float*)mask)[mi] != 0.f;
      if (!msk) {
        float dd = 0.f;
        const float* krow = Kt + s * 128;
#pragma unroll
        for (int j = 0; j < 128; j += 4) {
          float4 a = *(const float4*)(qrow + j);
          float4 b = *(const float4*)(krow + j);
          dd += a.x * b.x + a.y * b.y + a.z * b.z + a.w * b.w;
        }
        v = dd * 0.08838834764831845f;  // 1/sqrt(128)
      }
    }
    sc[s] = v;
  }
  __syncthreads();
  float m = fmaxf(sc[t], sc[t + 256]);
  for (int off = 32; off; off >>= 1) m = fmaxf(m, __shfl_down(m, off));
  if ((t & 63) == 0) red[t >> 6] = m;
  __syncthreads();
  m = fmaxf(fmaxf(red[0], red[1]), fmaxf(red[2], red[3]));
  float p0 = __expf(sc[t] - m), p1 = __expf(sc[t + 256] - m);
  float s2 = p0 + p1;
  for (int off = 32; off; off >>= 1) s2 += __shfl_down(s2, off);
  if ((t & 63) == 0) red[4 + (t >> 6)] = s2;
  __syncthreads();
  float inv = 1.f / (red[4] + red[5] + red[6] + red[7]);
  attn[d * S + t] = p0 * inv;
  if (t + 256 < S) attn[d * S + t + 256] = p1 * inv;
}

// ---------------- agg[b,d,:] = sum_s attn[d,s]*pat[b,s]*sub[s,:] ------------
__global__ __launch_bounds__(128) void agg_weighted(const float* __restrict__ attn, const float* __restrict__ pat,
                                                    const float* __restrict__ subf, float* __restrict__ aggT,
                                                    int D, int S) {
  int d = blockIdx.x, t = threadIdx.x;
  float acc[64];
#pragma unroll
  for (int b = 0; b < 64; b++) acc[b] = 0.f;
  for (int s = 0; s < S; s++) {
    float a = attn[d * S + s];
    if (a == 0.f) continue;      // masked entries are exactly 0; wave-uniform
    float as = a * subf[s * 128 + t];
#pragma unroll
    for (int b = 0; b < 64; b++) acc[b] = fmaf(as, pat[b * S + s], acc[b]);
  }
  for (int b = 0; b < 64; b++) aggT[((size_t)(b * D + d)) * 128 + t] = acc[b];
}

// ---------------- score head: sigmoid(relu(agg@w1+b1)@w2+b2) ---------------
__global__ __launch_bounds__(64) void score_head(const float* __restrict__ aggT,
                                                 const float* __restrict__ w1, const float* __restrict__ b1,
                                                 const float* __restrict__ w2, const float* __restrict__ b2,
                                                 float* __restrict__ out) {
  int i = blockIdx.x;     // i = b*D + d
  int j = threadIdx.x;    // 64
  const float* av = aggT + (size_t)i * 128;
  float acc = b1[j];
#pragma unroll 8
  for (int k = 0; k < 128; k++) acc = fmaf(av[k], w1[k * 64 + j], acc);
  acc = fmaxf(acc, 0.f) * w2[j];
  for (int off = 32; off; off >>= 1) acc += __shfl_down(acc, off);
  if (j == 0) {
    float x = acc + b2[0];
    out[i] = 1.f / (1.f + __expf(-x));
  }
}

// ---------------------------------------------------------------------------
extern "C" void kernel_launch(void* const* d_in, const int* in_sizes, int n_in,
                              void* d_out, int out_size, void* d_ws, size_t ws_size,
                              hipStream_t stream) {
  const float* atom_emb = (const float*)d_in[0];
  const float* bond_emb = (const float*)d_in[1];
  const float* gin_eps  = (const float*)d_in[2];
  const float* gin_w1   = (const float*)d_in[3];
  const float* gin_b1   = (const float*)d_in[4];
  const float* bn1g     = (const float*)d_in[5];
  const float* bn1b     = (const float*)d_in[6];
  const float* gin_w2   = (const float*)d_in[7];
  const float* gin_b2   = (const float*)d_in[8];
  const float* bn2g     = (const float*)d_in[9];
  const float* bn2b     = (const float*)d_in[10];
  const float* sab_wq = (const float*)d_in[11];
  const float* sab_wk = (const float*)d_in[12];
  const float* sab_wv = (const float*)d_in[13];
  const float* sab_wo = (const float*)d_in[14];
  const float* sab_bq = (const float*)d_in[15];
  const float* sab_bk = (const float*)d_in[16];
  const float* sab_bv = (const float*)d_in[17];
  const float* sab_bo = (const float*)d_in[18];
  const float* ln1b = (const float*)d_in[19];
  const float* ln2b = (const float*)d_in[20];
  const float* ln1g = (const float*)d_in[21];
  const float* ln2g = (const float*)d_in[22];
  const float* agg_wq = (const float*)d_in[23];
  const float* agg_bq = (const float*)d_in[24];
  const float* agg_wk = (const float*)d_in[25];
  const float* agg_bk = (const float*)d_in[26];
  const float* score_w1 = (const float*)d_in[27];
  const float* score_b1 = (const float*)d_in[28];
  const float* score_w2 = (const float*)d_in[29];
  const float* score_b2 = (const float*)d_in[30];
  const float* patient  = (const float*)d_in[31];
  const float* avgproj  = (const float*)d_in[32];
  const int* sub_x     = (const int*)d_in[33];
  const int* sub_ea    = (const int*)d_in[34];
  const int* sub_ei    = (const int*)d_in[35];
  const int* sub_batch = (const int*)d_in[36];
  const int* mol_x     = (const int*)d_in[37];
  const int* mol_ea    = (const int*)d_in[38];
  const int* mol_ei    = (const int*)d_in[39];
  const int* mol_batch = (const int*)d_in[40];
  const void* mask     = d_in[41];

  const int Ns = in_sizes[33] / 9, Es = in_sizes[34] / 3;
  const int Nm = in_sizes[37] / 9, Em = in_sizes[38] / 3;
  const int S = 492, M = 600, D = 200, B = 64;

  // ---- workspace carve-up (<= ~165 MB) ----
  char* Wp = (char*)d_ws;
  size_t off = 0;
  auto alloc = [&](size_t bytes) -> void* {
    void* p = Wp + off;
    off = (off + bytes + 255) & ~(size_t)255;
    return p;
  };
  int NR = ((Nm > Ns ? Nm : Ns) + 63) & ~63;
  float* h_buf   = (float*)alloc((size_t)NR * 128 * 4);
  float* agg_buf = (float*)alloc((size_t)NR * 128 * 4);
  unsigned short* w1t = (unsigned short*)alloc(262144 * 2);
  unsigned short* w2t = (unsigned short*)alloc(262144 * 2);
  char* zstart = Wp + off;                       // region zeroed below
  float* pooled_sub = (float*)alloc((size_t)S * 128 * 4);
  float* pooled_mol = (float*)alloc((size_t)M * 128 * 4);
  float* cnt_s = (float*)alloc(S * 4);
  float* cnt_m = (float*)alloc(M * 4);
  int* flags   = (int*)alloc(8);
  size_t zsize = (size_t)((Wp + off) - zstart);
  float* Qb   = (float*)alloc((size_t)S * 128 * 4);
  float* Kb   = (float*)alloc((size_t)S * 128 * 4);
  float* Vb   = (float*)alloc((size_t)S * 128 * 4);
  float* Ob   = (float*)alloc((size_t)S * 128 * 4);
  float* O2b  = (float*)alloc((size_t)S * 128 * 4);
  float* subf = (float*)alloc((size_t)S * 128 * 4);
  float* mol_embb = (float*)alloc((size_t)D * 128 * 4);
  float* aggQb = (float*)alloc((size_t)D * 128 * 4);
  float* aggKb = (float*)alloc((size_t)S * 128 * 4);
  float* attnb = (float*)alloc((size_t)D * S * 4);
  float* aggTb = (float*)alloc((size_t)B * D * 128 * 4);
  (void)ws_size; (void)n_in; (void)out_size;

  hipMemsetAsync(zstart, 0, zsize, stream);
  prep_weights<<<1024, 256, 0, stream>>>(gin_w1, gin_w2, w1t, w2t);
  mask_detect<<<(D * S + 255) / 256, 256, 0, stream>>>((const unsigned char*)mask, flags, D * S);

  auto run_gin = [&](int g, int N, int E, const int* x, const int* ea, const int* ei,
                     const int* batch, float* pooled, float* cnt, int Sg) {
    embed_nodes<<<(N * 128 + 255) / 256, 256, 0, stream>>>(
        x, atom_emb + (size_t)g * 9 * 64 * 128, h_buf, agg_buf, N);
    for (int l = 0; l < 4; l++) {
      int gl = g * 4 + l;
      edge_msg<<<(E * 128 + 255) / 256, 256, 0, stream>>>(
          ei, ea, bond_emb + (size_t)gl * 3 * 64 * 128, h_buf, agg_buf, E);
      gin_mlp<<<(N + 63) / 64, 256, 0, stream>>>(
          h_buf, agg_buf, gin_eps + gl,
          w1t + (size_t)gl * 32768, gin_b1 + gl * 256, bn1g + gl * 256, bn1b + gl * 256,
          w2t + (size_t)gl * 32768, gin_b2 + gl * 128, bn2g + gl * 128, bn2b + gl * 128,
          N, (l != 3) ? 1 : 0);
    }
    pool_add<<<(N * 128 + 255) / 256, 256, 0, stream>>>(h_buf, batch, pooled, cnt, N);
    pool_div<<<(Sg * 128 + 255) / 256, 256, 0, stream>>>(pooled, cnt, Sg * 128);
  };

  // --- substructure encoder + SAB ---
  run_gin(0, Ns, Es, sub_x, sub_ea, sub_ei, sub_batch, pooled_sub, cnt_s, S);
  gemm_small<<<(S * 128 + 255) / 256, 256, 0, stream>>>(pooled_sub, sab_wq, sab_bq, Qb, S, 128, 128);
  gemm_small<<<(S * 128 + 255) / 256, 256, 0, stream>>>(pooled_sub, sab_wk, sab_bk, Kb, S, 128, 128);
  gemm_small<<<(S * 128 + 255) / 256, 256, 0, stream>>>(pooled_sub, sab_wv, sab_bv, Vb, S, 128, 128);
  sab_attn<<<dim3(S, 2), 256, 0, stream>>>(Qb, Kb, Vb, Ob, S);
  ln_rows<<<S, 128, 0, stream>>>(Ob, Ob, ln1g, ln1b);
  gemm_small<<<(S * 128 + 255) / 256, 256, 0, stream>>>(Ob, sab_wo, sab_bo, O2b, S, 128, 128);
  ln_rows<<<S, 128, 0, stream>>>(O2b, subf, ln2g, ln2b);

  // --- molecule encoder + projection ---
  run_gin(1, Nm, Em, mol_x, mol_ea, mol_ei, mol_batch, pooled_mol, cnt_m, M);
  gemm_small<<<(D * 128 + 255) / 256, 256, 0, stream>>>(avgproj, pooled_mol, (const float*)nullptr, mol_embb, D, 128, M);

  // --- attention aggregation + score ---
  gemm_small<<<(D * 128 + 255) / 256, 256, 0, stream>>>(mol_embb, agg_wq, agg_bq, aggQb, D, 128, 128);
  gemm_small<<<(S * 128 + 255) / 256, 256, 0, stream>>>(subf, agg_wk, agg_bk, aggKb, S, 128, 128);
  agg_attn<<<D, 256, 0, stream>>>(aggQb, aggKb, mask, flags, attnb, D, S);
  agg_weighted<<<D, 128, 0, stream>>>(attnb, patient, subf, aggTb, D, S);
  score_head<<<B * D, 64, 0, stream>>>(aggTb, score_w1, score_b1, score_w2, score_b2, (float*)d_out);
}

// Round 2
// 2379.977 us; speedup vs baseline: 1.1257x; 1.1257x over previous
//
#include <hip/hip_runtime.h>

// ---------------------------------------------------------------------------
// MoleRec pipeline on gfx950.
// Structure:
//   prep: transpose+bf16 GIN MLP weights; detect mask byte-layout
//   per graph (sub, mol): embed -> 4x(edge_msg -> gin_mlp[MFMA]) -> mean pool
//   SAB on sub (492x128), mol_emb = avgproj @ mol_pool
//   masked softmax attention -> weighted agg (MFMA) -> score head -> sigmoid
// R1: agg_weighted (398us, latency-bound serial loop) replaced by per-d
//     64x128x492 bf16 MFMA GEMM with A=(pat .* attn[d]) staged in LDS and
//     B=subT bf16 [128][512] read from L2 (shared across all 200 blocks).
// ---------------------------------------------------------------------------

typedef short short8 __attribute__((ext_vector_type(8)));
typedef float f32x4 __attribute__((ext_vector_type(4)));
typedef unsigned short us4 __attribute__((ext_vector_type(4)));

#define BN_RSQ 0.9999950000374997f   // 1/sqrt(1+1e-5)  (BatchNorm eval, var=1)
#define LN_EPS 1e-5f
#define NEGBIG -4294967296.0f        // -(1<<32), matches reference mask fill

__device__ __forceinline__ unsigned short f2bf(float x) {
  union { float f; unsigned int u; } v; v.f = x;
  unsigned int r = v.u + 0x7fffu + ((v.u >> 16) & 1u);   // RNE
  return (unsigned short)(r >> 16);
}

// ---------------- weight prep: fp32 [K][N] -> bf16 [N][K] ------------------
__global__ void prep_weights(const float* __restrict__ w1, const float* __restrict__ w2,
                             unsigned short* __restrict__ w1t, unsigned short* __restrict__ w2t) {
  int i = blockIdx.x * 256 + threadIdx.x;
  if (i >= 262144) return;
  int gl = i >> 15;
  // w1: [2][4][128][256] -> w1t[gl][n=256][k=128]
  int k1 = (i >> 8) & 127, c1 = i & 255;
  w1t[(gl << 15) + c1 * 128 + k1] = f2bf(w1[i]);
  // w2: [2][4][256][128] -> w2t[gl][n=128][k=256]
  int k2 = (i >> 7) & 255, c2 = i & 127;
  w2t[(gl << 15) + c2 * 256 + k2] = f2bf(w2[i]);
}

// ---------------- mask layout detection ------------------------------------
__global__ void mask_detect(const unsigned char* __restrict__ m, int* __restrict__ flags, int nbytes) {
  int i = blockIdx.x * 256 + threadIdx.x;
  if (i < nbytes && m[i]) {
    if ((i & 3) == 0) atomicOr(flags, 1);
    else atomicOr(flags + 1, 1);
  }
}

// ---------------- node embedding (also zeroes agg) --------------------------
__global__ void embed_nodes(const int* __restrict__ x, const float* __restrict__ table,
                            float* __restrict__ h, float* __restrict__ agg, int N) {
  int i = blockIdx.x * 256 + threadIdx.x;
  if (i >= N * 128) return;
  int n = i >> 7, c = i & 127;
  float s = 0.f;
#pragma unroll
  for (int f = 0; f < 9; f++) {
    int v = x[n * 9 + f];
    s += table[(f * 64 + v) * 128 + c];
  }
  h[i] = s;
  agg[i] = 0.f;
}

// ---------------- edge messages: relu(h[src]+bond_emb) scattered to tgt -----
__global__ void edge_msg(const int* __restrict__ ei, const int* __restrict__ attr,
                         const float* __restrict__ bt, const float* __restrict__ h,
                         float* __restrict__ agg, int E) {
  int i = blockIdx.x * 256 + threadIdx.x;
  if (i >= E * 128) return;
  int e = i >> 7, c = i & 127;
  int tgt = ei[e], src = ei[E + e];
  float v = h[src * 128 + c];
  v += bt[(0 * 64 + attr[e * 3 + 0]) * 128 + c];
  v += bt[(1 * 64 + attr[e * 3 + 1]) * 128 + c];
  v += bt[(2 * 64 + attr[e * 3 + 2]) * 128 + c];
  v = fmaxf(v, 0.f);
  atomicAdd(&agg[tgt * 128 + c], v);
}

// ---------------- fused GIN MLP: h = bn2(relu(bn1(z@w1+b1))@w2+b2) ---------
__global__ __launch_bounds__(256) void gin_mlp(
    float* __restrict__ h, float* __restrict__ agg, const float* __restrict__ eps_p,
    const unsigned short* __restrict__ w1t, const float* __restrict__ b1,
    const float* __restrict__ g1, const float* __restrict__ be1,
    const unsigned short* __restrict__ w2t, const float* __restrict__ b2,
    const float* __restrict__ g2, const float* __restrict__ be2,
    int N, int do_relu) {
  __shared__ unsigned short zs[64][136];    // 64x128 bf16, +8 pad
  __shared__ unsigned short z1s[64][264];   // 64x256 bf16, +8 pad
  int t = threadIdx.x;
  int r0 = blockIdx.x * 64;
  float eps1 = 1.0f + *eps_p;
  for (int i = t; i < 2048; i += 256) {
    int r = i >> 5;
    int c4 = (i & 31) << 2;
    int n = r0 + r;
    us4 o;
    if (n < N) {
      float4 hv = *(const float4*)(h + n * 128 + c4);
      float4 av = *(const float4*)(agg + n * 128 + c4);
      o.x = f2bf(fmaf(eps1, hv.x, av.x));
      o.y = f2bf(fmaf(eps1, hv.y, av.y));
      o.z = f2bf(fmaf(eps1, hv.z, av.z));
      o.w = f2bf(fmaf(eps1, hv.w, av.w));
      *(float4*)(agg + n * 128 + c4) = make_float4(0.f, 0.f, 0.f, 0.f);
    } else {
      o.x = 0; o.y = 0; o.z = 0; o.w = 0;
    }
    *(us4*)&zs[r][c4] = o;
  }
  __syncthreads();
  int lane = t & 63, wave = t >> 6;
  int quad = lane >> 4, l16 = lane & 15;
  {
    short8 bw[4][4];
    int cb = wave * 64;
#pragma unroll
    for (int nt = 0; nt < 4; nt++) {
      const unsigned short* p = w1t + (cb + nt * 16 + l16) * 128 + quad * 8;
#pragma unroll
      for (int kc = 0; kc < 4; kc++) bw[nt][kc] = *(const short8*)(p + kc * 32);
    }
#pragma unroll
    for (int mt = 0; mt < 4; mt++) {
      short8 af[4];
#pragma unroll
      for (int kc = 0; kc < 4; kc++)
        af[kc] = *(const short8*)&zs[mt * 16 + l16][kc * 32 + quad * 8];
#pragma unroll
      for (int nt = 0; nt < 4; nt++) {
        f32x4 acc = {0.f, 0.f, 0.f, 0.f};
#pragma unroll
        for (int kc = 0; kc < 4; kc++)
          acc = __builtin_amdgcn_mfma_f32_16x16x32_bf16(af[kc], bw[nt][kc], acc, 0, 0, 0);
        int c = cb + nt * 16 + l16;
        float sc = g1[c] * BN_RSQ, sh = be1[c], bb = b1[c];
#pragma unroll
        for (int reg = 0; reg < 4; reg++) {
          int r = mt * 16 + quad * 4 + reg;
          float y = (acc[reg] + bb) * sc + sh;
          z1s[r][c] = f2bf(fmaxf(y, 0.f));
        }
      }
    }
  }
  __syncthreads();
  {
    short8 bw[2][8];
    int cb = wave * 32;
#pragma unroll
    for (int nt = 0; nt < 2; nt++) {
      const unsigned short* p = w2t + (cb + nt * 16 + l16) * 256 + quad * 8;
#pragma unroll
      for (int kc = 0; kc < 8; kc++) bw[nt][kc] = *(const short8*)(p + kc * 32);
    }
#pragma unroll
    for (int mt = 0; mt < 4; mt++) {
      short8 af[8];
#pragma unroll
      for (int kc = 0; kc < 8; kc++)
        af[kc] = *(const short8*)&z1s[mt * 16 + l16][kc * 32 + quad * 8];
#pragma unroll
      for (int nt = 0; nt < 2; nt++) {
        f32x4 acc = {0.f, 0.f, 0.f, 0.f};
#pragma unroll
        for (int kc = 0; kc < 8; kc++)
          acc = __builtin_amdgcn_mfma_f32_16x16x32_bf16(af[kc], bw[nt][kc], acc, 0, 0, 0);
        int c = cb + nt * 16 + l16;
        float sc = g2[c] * BN_RSQ, sh = be2[c], bb = b2[c];
#pragma unroll
        for (int reg = 0; reg < 4; reg++) {
          int n = r0 + mt * 16 + quad * 4 + reg;
          if (n < N) {
            float y = (acc[reg] + bb) * sc + sh;
            if (do_relu) y = fmaxf(y, 0.f);
            h[n * 128 + c] = y;
          }
        }
      }
    }
  }
}

// ---------------- mean pooling ---------------------------------------------
__global__ void pool_add(const float* __restrict__ h, const int* __restrict__ batch,
                         float* __restrict__ pooled, float* __restrict__ cnt, int N) {
  int i = blockIdx.x * 256 + threadIdx.x;
  if (i >= N * 128) return;
  int n = i >> 7, c = i & 127;
  int b = batch[n];
  atomicAdd(&pooled[b * 128 + c], h[i]);
  if (c == 0) atomicAdd(&cnt[b], 1.0f);
}

__global__ void pool_div(float* __restrict__ pooled, const float* __restrict__ cnt, int total) {
  int i = blockIdx.x * 256 + threadIdx.x;
  if (i >= total) return;
  pooled[i] = pooled[i] / (cnt[i >> 7] + 1e-9f);
}

// ---------------- small generic GEMM: C = A[MxK] @ W[KxN] + bias -----------
__global__ void gemm_small(const float* __restrict__ A, const float* __restrict__ W,
                           const float* __restrict__ bias, float* __restrict__ C,
                           int M, int N, int K) {
  int i = blockIdx.x * 256 + threadIdx.x;
  if (i >= M * N) return;
  int r = i / N, c = i - r * N;
  float acc = bias ? bias[c] : 0.f;
  const float* a = A + (size_t)r * K;
  for (int k = 0; k < K; k++) acc = fmaf(a[k], W[(size_t)k * N + c], acc);
  C[i] = acc;
}

// ---------------- SAB attention: O = Qs + softmax(QsKs^T/8) Vs -------------
__global__ __launch_bounds__(256) void sab_attn(const float* __restrict__ Q, const float* __restrict__ K,
                                                const float* __restrict__ V, float* __restrict__ O, int S) {
  int q = blockIdx.x, hd = blockIdx.y;
  int t = threadIdx.x;
  __shared__ float sc[512];
  __shared__ float red[8];
  __shared__ float pacc[4][64];
  const float* qrow = Q + q * 128 + hd * 64;
  for (int k = t; k < 512; k += 256) {
    float d = -1e30f;
    if (k < S) {
      const float* krow = K + k * 128 + hd * 64;
      d = 0.f;
#pragma unroll
      for (int j = 0; j < 64; j += 4) {
        float4 a = *(const float4*)(qrow + j);
        float4 b = *(const float4*)(krow + j);
        d += a.x * b.x + a.y * b.y + a.z * b.z + a.w * b.w;
      }
      d *= 0.125f;   // 1/sqrt(64)
    }
    sc[k] = d;
  }
  __syncthreads();
  float m = fmaxf(sc[t], sc[t + 256]);
  for (int off = 32; off; off >>= 1) m = fmaxf(m, __shfl_down(m, off));
  if ((t & 63) == 0) red[t >> 6] = m;
  __syncthreads();
  m = fmaxf(fmaxf(red[0], red[1]), fmaxf(red[2], red[3]));
  float p0 = __expf(sc[t] - m), p1 = __expf(sc[t + 256] - m);
  sc[t] = p0; sc[t + 256] = p1;
  float s = p0 + p1;
  for (int off = 32; off; off >>= 1) s += __shfl_down(s, off);
  if ((t & 63) == 0) red[4 + (t >> 6)] = s;
  __syncthreads();
  float inv = 1.f / (red[4] + red[5] + red[6] + red[7]);
  int d = t & 63, part = t >> 6;
  float acc = 0.f;
  for (int k = part; k < S; k += 4) acc += sc[k] * V[k * 128 + hd * 64 + d];
  pacc[part][d] = acc;
  __syncthreads();
  if (part == 0) {
    float o = (pacc[0][d] + pacc[1][d] + pacc[2][d] + pacc[3][d]) * inv;
    O[q * 128 + hd * 64 + d] = qrow[d] + o;
  }
}

// ---------------- row LayerNorm over 128 ------------------------------------
__global__ __launch_bounds__(128) void ln_rows(const float* __restrict__ in, float* __restrict__ out,
                                               const float* __restrict__ g, const float* __restrict__ b) {
  int r = blockIdx.x, t = threadIdx.x;
  __shared__ float red[4];
  float x = in[r * 128 + t];
  float s = x;
  for (int off = 32; off; off >>= 1) s += __shfl_down(s, off);
  if ((t & 63) == 0) red[t >> 6] = s;
  __syncthreads();
  float mu = (red[0] + red[1]) * (1.f / 128.f);
  float dd = x - mu;
  float v = dd * dd;
  for (int off = 32; off; off >>= 1) v += __shfl_down(v, off);
  if ((t & 63) == 0) red[2 + (t >> 6)] = v;
  __syncthreads();
  float var = (red[2] + red[3]) * (1.f / 128.f);
  out[r * 128 + t] = g[t] * dd * rsqrtf(var + LN_EPS) + b[t];
}

// ---------------- masked softmax attn: attn[d,s] ----------------------------
__global__ __launch_bounds__(256) void agg_attn(const float* __restrict__ Q, const float* __restrict__ Kt,
                                                const void* __restrict__ mask, const int* __restrict__ flags,
                                                float* __restrict__ attn, int D, int S) {
  int d = blockIdx.x, t = threadIdx.x;
  __shared__ float sc[512];
  __shared__ float red[8];
  int layout = (flags[1] == 0) ? 0 : (flags[0] ? 1 : 2);
  const float* qrow = Q + d * 128;
  for (int s = t; s < 512; s += 256) {
    float v = NEGBIG;
    if (s < S) {
      int mi = d * S + s;
      bool msk;
      if (layout == 0)      msk = ((const int*)mask)[mi] != 0;
      else if (layout == 1) msk = ((const unsigned char*)mask)[mi] != 0;
      else                  msk = ((const float*)mask)[mi] != 0.f;
      if (!msk) {
        float dd = 0.f;
        const float* krow = Kt + s * 128;
#pragma unroll
        for (int j = 0; j < 128; j += 4) {
          float4 a = *(const float4*)(qrow + j);
          float4 b = *(const float4*)(krow + j);
          dd += a.x * b.x + a.y * b.y + a.z * b.z + a.w * b.w;
        }
        v = dd * 0.08838834764831845f;  // 1/sqrt(128)
      }
    }
    sc[s] = v;
  }
  __syncthreads();
  float m = fmaxf(sc[t], sc[t + 256]);
  for (int off = 32; off; off >>= 1) m = fmaxf(m, __shfl_down(m, off));
  if ((t & 63) == 0) red[t >> 6] = m;
  __syncthreads();
  m = fmaxf(fmaxf(red[0], red[1]), fmaxf(red[2], red[3]));
  float p0 = __expf(sc[t] - m), p1 = __expf(sc[t + 256] - m);
  float s2 = p0 + p1;
  for (int off = 32; off; off >>= 1) s2 += __shfl_down(s2, off);
  if ((t & 63) == 0) red[4 + (t >> 6)] = s2;
  __syncthreads();
  float inv = 1.f / (red[4] + red[5] + red[6] + red[7]);
  attn[d * S + t] = p0 * inv;
  if (t + 256 < S) attn[d * S + t + 256] = p1 * inv;
}

// ---------------- subT prep: subf [S][128] f32 -> subT bf16 [128][512] ------
__global__ void prep_subT(const float* __restrict__ subf, unsigned short* __restrict__ subT, int S) {
  int i = blockIdx.x * 256 + threadIdx.x;   // 128*512
  if (i >= 128 * 512) return;
  int hh = i >> 9, k = i & 511;
  subT[i] = (k < S) ? f2bf(subf[k * 128 + hh]) : (unsigned short)0;
}

// ---------------- agg via MFMA: per d, (pat .* attn[d])[64x492] @ sub -------
// aggT[(b*D+d)*128 + h] = sum_s attn[d,s]*pat[b,s]*sub[s,h]
__global__ __launch_bounds__(256) void agg_mfma(const float* __restrict__ attn, const float* __restrict__ pat,
                                                const unsigned short* __restrict__ subT,
                                                float* __restrict__ aggT, int D, int S) {
  int d = blockIdx.x, t = threadIdx.x;
  __shared__ unsigned short As[64][40];   // 64 rows(b) x 32 k bf16, pad->40 (80B rows, 16B-aligned)
  int lane = t & 63, wave = t >> 6;
  int quad = lane >> 4, l16 = lane & 15;
  f32x4 acc[8];
#pragma unroll
  for (int nt = 0; nt < 8; nt++) acc[nt] = (f32x4){0.f, 0.f, 0.f, 0.f};
  const float* arow = attn + d * S;
  int srow = t >> 2, skb = (t & 3) * 8;   // staging: row b=srow, k-offset skb
  for (int c = 0; c < 16; c++) {
    int s0 = c * 32;
    __syncthreads();                      // previous chunk's reads done
    unsigned short v[8];
#pragma unroll
    for (int j = 0; j < 8; j++) {
      int s = s0 + skb + j;
      float x = (s < S) ? arow[s] * pat[srow * S + s] : 0.f;
      v[j] = f2bf(x);
    }
    *(us4*)&As[srow][skb]     = *(us4*)&v[0];
    *(us4*)&As[srow][skb + 4] = *(us4*)&v[4];
    __syncthreads();
    short8 af = *(const short8*)&As[16 * wave + l16][quad * 8];
#pragma unroll
    for (int nt = 0; nt < 8; nt++) {
      short8 bf = *(const short8*)(subT + (nt * 16 + l16) * 512 + s0 + quad * 8);
      acc[nt] = __builtin_amdgcn_mfma_f32_16x16x32_bf16(af, bf, acc[nt], 0, 0, 0);
    }
  }
  // C/D layout: row(b of tile) = quad*4+reg, col(h) = l16
#pragma unroll
  for (int nt = 0; nt < 8; nt++) {
    int hh = nt * 16 + l16;
#pragma unroll
    for (int reg = 0; reg < 4; reg++) {
      int b = 16 * wave + quad * 4 + reg;
      aggT[((size_t)(b * D + d)) * 128 + hh] = acc[nt][reg];
    }
  }
}

// ---------------- score head: sigmoid(relu(agg@w1+b1)@w2+b2) ---------------
__global__ __launch_bounds__(64) void score_head(const float* __restrict__ aggT,
                                                 const float* __restrict__ w1, const float* __restrict__ b1,
                                                 const float* __restrict__ w2, const float* __restrict__ b2,
                                                 float* __restrict__ out) {
  int i = blockIdx.x;     // i = b*D + d
  int j = threadIdx.x;    // 64
  const float* av = aggT + (size_t)i * 128;
  float acc = b1[j];
#pragma unroll 8
  for (int k = 0; k < 128; k++) acc = fmaf(av[k], w1[k * 64 + j], acc);
  acc = fmaxf(acc, 0.f) * w2[j];
  for (int off = 32; off; off >>= 1) acc += __shfl_down(acc, off);
  if (j == 0) {
    float x = acc + b2[0];
    out[i] = 1.f / (1.f + __expf(-x));
  }
}

// ---------------------------------------------------------------------------
extern "C" void kernel_launch(void* const* d_in, const int* in_sizes, int n_in,
                              void* d_out, int out_size, void* d_ws, size_t ws_size,
                              hipStream_t stream) {
  const float* atom_emb = (const float*)d_in[0];
  const float* bond_emb = (const float*)d_in[1];
  const float* gin_eps  = (const float*)d_in[2];
  const float* gin_w1   = (const float*)d_in[3];
  const float* gin_b1   = (const float*)d_in[4];
  const float* bn1g     = (const float*)d_in[5];
  const float* bn1b     = (const float*)d_in[6];
  const float* gin_w2   = (const float*)d_in[7];
  const float* gin_b2   = (const float*)d_in[8];
  const float* bn2g     = (const float*)d_in[9];
  const float* bn2b     = (const float*)d_in[10];
  const float* sab_wq = (const float*)d_in[11];
  const float* sab_wk = (const float*)d_in[12];
  const float* sab_wv = (const float*)d_in[13];
  const float* sab_wo = (const float*)d_in[14];
  const float* sab_bq = (const float*)d_in[15];
  const float* sab_bk = (const float*)d_in[16];
  const float* sab_bv = (const float*)d_in[17];
  const float* sab_bo = (const float*)d_in[18];
  const float* ln1b = (const float*)d_in[19];
  const float* ln2b = (const float*)d_in[20];
  const float* ln1g = (const float*)d_in[21];
  const float* ln2g = (const float*)d_in[22];
  const float* agg_wq = (const float*)d_in[23];
  const float* agg_bq = (const float*)d_in[24];
  const float* agg_wk = (const float*)d_in[25];
  const float* agg_bk = (const float*)d_in[26];
  const float* score_w1 = (const float*)d_in[27];
  const float* score_b1 = (const float*)d_in[28];
  const float* score_w2 = (const float*)d_in[29];
  const float* score_b2 = (const float*)d_in[30];
  const float* patient  = (const float*)d_in[31];
  const float* avgproj  = (const float*)d_in[32];
  const int* sub_x     = (const int*)d_in[33];
  const int* sub_ea    = (const int*)d_in[34];
  const int* sub_ei    = (const int*)d_in[35];
  const int* sub_batch = (const int*)d_in[36];
  const int* mol_x     = (const int*)d_in[37];
  const int* mol_ea    = (const int*)d_in[38];
  const int* mol_ei    = (const int*)d_in[39];
  const int* mol_batch = (const int*)d_in[40];
  const void* mask     = d_in[41];

  const int Ns = in_sizes[33] / 9, Es = in_sizes[34] / 3;
  const int Nm = in_sizes[37] / 9, Em = in_sizes[38] / 3;
  const int S = 492, M = 600, D = 200, B = 64;

  // ---- workspace carve-up ----
  char* Wp = (char*)d_ws;
  size_t off = 0;
  auto alloc = [&](size_t bytes) -> void* {
    void* p = Wp + off;
    off = (off + bytes + 255) & ~(size_t)255;
    return p;
  };
  int NR = ((Nm > Ns ? Nm : Ns) + 63) & ~63;
  float* h_buf   = (float*)alloc((size_t)NR * 128 * 4);
  float* agg_buf = (float*)alloc((size_t)NR * 128 * 4);
  unsigned short* w1t = (unsigned short*)alloc(262144 * 2);
  unsigned short* w2t = (unsigned short*)alloc(262144 * 2);
  char* zstart = Wp + off;                       // region zeroed below
  float* pooled_sub = (float*)alloc((size_t)S * 128 * 4);
  float* pooled_mol = (float*)alloc((size_t)M * 128 * 4);
  float* cnt_s = (float*)alloc(S * 4);
  float* cnt_m = (float*)alloc(M * 4);
  int* flags   = (int*)alloc(8);
  size_t zsize = (size_t)((Wp + off) - zstart);
  float* Qb   = (float*)alloc((size_t)S * 128 * 4);
  float* Kb   = (float*)alloc((size_t)S * 128 * 4);
  float* Vb   = (float*)alloc((size_t)S * 128 * 4);
  float* Ob   = (float*)alloc((size_t)S * 128 * 4);
  float* O2b  = (float*)alloc((size_t)S * 128 * 4);
  float* subf = (float*)alloc((size_t)S * 128 * 4);
  unsigned short* subT = (unsigned short*)alloc((size_t)128 * 512 * 2);
  float* mol_embb = (float*)alloc((size_t)D * 128 * 4);
  float* aggQb = (float*)alloc((size_t)D * 128 * 4);
  float* aggKb = (float*)alloc((size_t)S * 128 * 4);
  float* attnb = (float*)alloc((size_t)D * S * 4);
  float* aggTb = (float*)alloc((size_t)B * D * 128 * 4);
  (void)ws_size; (void)n_in; (void)out_size;

  hipMemsetAsync(zstart, 0, zsize, stream);
  prep_weights<<<1024, 256, 0, stream>>>(gin_w1, gin_w2, w1t, w2t);
  mask_detect<<<(D * S + 255) / 256, 256, 0, stream>>>((const unsigned char*)mask, flags, D * S);

  auto run_gin = [&](int g, int N, int E, const int* x, const int* ea, const int* ei,
                     const int* batch, float* pooled, float* cnt, int Sg) {
    embed_nodes<<<(N * 128 + 255) / 256, 256, 0, stream>>>(
        x, atom_emb + (size_t)g * 9 * 64 * 128, h_buf, agg_buf, N);
    for (int l = 0; l < 4; l++) {
      int gl = g * 4 + l;
      edge_msg<<<(E * 128 + 255) / 256, 256, 0, stream>>>(
          ei, ea, bond_emb + (size_t)gl * 3 * 64 * 128, h_buf, agg_buf, E);
      gin_mlp<<<(N + 63) / 64, 256, 0, stream>>>(
          h_buf, agg_buf, gin_eps + gl,
          w1t + (size_t)gl * 32768, gin_b1 + gl * 256, bn1g + gl * 256, bn1b + gl * 256,
          w2t + (size_t)gl * 32768, gin_b2 + gl * 128, bn2g + gl * 128, bn2b + gl * 128,
          N, (l != 3) ? 1 : 0);
    }
    pool_add<<<(N * 128 + 255) / 256, 256, 0, stream>>>(h_buf, batch, pooled, cnt, N);
    pool_div<<<(Sg * 128 + 255) / 256, 256, 0, stream>>>(pooled, cnt, Sg * 128);
  };

  // --- substructure encoder + SAB ---
  run_gin(0, Ns, Es, sub_x, sub_ea, sub_ei, sub_batch, pooled_sub, cnt_s, S);
  gemm_small<<<(S * 128 + 255) / 256, 256, 0, stream>>>(pooled_sub, sab_wq, sab_bq, Qb, S, 128, 128);
  gemm_small<<<(S * 128 + 255) / 256, 256, 0, stream>>>(pooled_sub, sab_wk, sab_bk, Kb, S, 128, 128);
  gemm_small<<<(S * 128 + 255) / 256, 256, 0, stream>>>(pooled_sub, sab_wv, sab_bv, Vb, S, 128, 128);
  sab_attn<<<dim3(S, 2), 256, 0, stream>>>(Qb, Kb, Vb, Ob, S);
  ln_rows<<<S, 128, 0, stream>>>(Ob, Ob, ln1g, ln1b);
  gemm_small<<<(S * 128 + 255) / 256, 256, 0, stream>>>(Ob, sab_wo, sab_bo, O2b, S, 128, 128);
  ln_rows<<<S, 128, 0, stream>>>(O2b, subf, ln2g, ln2b);
  prep_subT<<<(128 * 512 + 255) / 256, 256, 0, stream>>>(subf, subT, S);

  // --- molecule encoder + projection ---
  run_gin(1, Nm, Em, mol_x, mol_ea, mol_ei, mol_batch, pooled_mol, cnt_m, M);
  gemm_small<<<(D * 128 + 255) / 256, 256, 0, stream>>>(avgproj, pooled_mol, (const float*)nullptr, mol_embb, D, 128, M);

  // --- attention aggregation + score ---
  gemm_small<<<(D * 128 + 255) / 256, 256, 0, stream>>>(mol_embb, agg_wq, agg_bq, aggQb, D, 128, 128);
  gemm_small<<<(S * 128 + 255) / 256, 256, 0, stream>>>(subf, agg_wk, agg_bk, aggKb, S, 128, 128);
  agg_attn<<<D, 256, 0, stream>>>(aggQb, aggKb, mask, flags, attnb, D, S);
  agg_mfma<<<D, 256, 0, stream>>>(attnb, patient, subT, aggTb, D, S);
  score_head<<<B * D, 64, 0, stream>>>(aggTb, score_w1, score_b1, score_w2, score_b2, (float*)d_out);
}

// Round 3
// 2184.001 us; speedup vs baseline: 1.2267x; 1.0897x over previous
//
#include <hip/hip_runtime.h>

// ---------------------------------------------------------------------------
// MoleRec pipeline on gfx950.
// R2: all fp32 global atomics removed (they write through past L2 on CDNA4:
//     pool_add showed 80MB WRITE_SIZE for a 307KB output). Edge aggregation
//     is fused into the GIN MLP via a CSR gather (built once per launch by
//     count->scan->scatter; edge structure is layer-invariant), h is
//     double-buffered, and pooling is CSR-segment based.
// ---------------------------------------------------------------------------

typedef short short8 __attribute__((ext_vector_type(8)));
typedef float f32x4 __attribute__((ext_vector_type(4)));
typedef unsigned short us4 __attribute__((ext_vector_type(4)));

#define BN_RSQ 0.9999950000374997f   // 1/sqrt(1+1e-5)  (BatchNorm eval, var=1)
#define LN_EPS 1e-5f
#define NEGBIG -4294967296.0f        // -(1<<32), matches reference mask fill

__device__ __forceinline__ unsigned short f2bf(float x) {
  union { float f; unsigned int u; } v; v.f = x;
  unsigned int r = v.u + 0x7fffu + ((v.u >> 16) & 1u);   // RNE
  return (unsigned short)(r >> 16);
}

// ---------------- weight prep: fp32 [K][N] -> bf16 [N][K] ------------------
__global__ void prep_weights(const float* __restrict__ w1, const float* __restrict__ w2,
                             unsigned short* __restrict__ w1t, unsigned short* __restrict__ w2t) {
  int i = blockIdx.x * 256 + threadIdx.x;
  if (i >= 262144) return;
  int gl = i >> 15;
  int k1 = (i >> 8) & 127, c1 = i & 255;
  w1t[(gl << 15) + c1 * 128 + k1] = f2bf(w1[i]);
  int k2 = (i >> 7) & 255, c2 = i & 127;
  w2t[(gl << 15) + c2 * 256 + k2] = f2bf(w2[i]);
}

// ---------------- mask layout detection ------------------------------------
__global__ void mask_detect(const unsigned char* __restrict__ m, int* __restrict__ flags, int nbytes) {
  int i = blockIdx.x * 256 + threadIdx.x;
  if (i < nbytes && m[i]) {
    if ((i & 3) == 0) atomicOr(flags, 1);
    else atomicOr(flags + 1, 1);
  }
}

// ---------------- CSR build: count ------------------------------------------
// deg_e indexed: [0..Nm) mol node tgt, [Nm..Nm+Ns) sub node tgt
// deg_n indexed: [0..M) mol batch seg, [M..M+S) sub batch seg
__global__ void build_count(const int* __restrict__ ei_m, int Em,
                            const int* __restrict__ ei_s, int Es,
                            const int* __restrict__ bm, int Nm,
                            const int* __restrict__ bs, int Ns,
                            int* __restrict__ deg_e, int* __restrict__ deg_n, int M) {
  int i = blockIdx.x * 256 + threadIdx.x;
  if (i < Em) { atomicAdd(&deg_e[ei_m[i]], 1); return; }
  i -= Em;
  if (i < Es) { atomicAdd(&deg_e[Nm + ei_s[i]], 1); return; }
  i -= Es;
  if (i < Nm) { atomicAdd(&deg_n[bm[i]], 1); return; }
  i -= Nm;
  if (i < Ns) { atomicAdd(&deg_n[M + bs[i]], 1); }
}

// ---------------- CSR build: block-level exclusive scan ---------------------
__global__ __launch_bounds__(256) void scan_block(const int* __restrict__ cnt, int n,
                                                  int* __restrict__ excl, int* __restrict__ bsum) {
  int gid = blockIdx.x * 256 + threadIdx.x;
  int lane = threadIdx.x & 63, w = threadIdx.x >> 6;
  int v = (gid < n) ? cnt[gid] : 0;
  int x = v;
#pragma unroll
  for (int off = 1; off < 64; off <<= 1) {
    int y = __shfl_up(x, off, 64);
    if (lane >= off) x += y;
  }
  __shared__ int wt[4];
  if (lane == 63) wt[w] = x;
  __syncthreads();
  int add = 0;
  for (int i = 0; i < w; i++) add += wt[i];
  x += add;
  if (gid < n) excl[gid] = x - v;
  if (threadIdx.x == 255) bsum[blockIdx.x] = x;
}

// scan of block sums in place (n <= 1024), result exclusive
__global__ __launch_bounds__(1024) void scan_top(int* __restrict__ bsum, int n) {
  int t = threadIdx.x;
  int lane = t & 63, w = t >> 6;
  int v = (t < n) ? bsum[t] : 0;
  int x = v;
#pragma unroll
  for (int off = 1; off < 64; off <<= 1) {
    int y = __shfl_up(x, off, 64);
    if (lane >= off) x += y;
  }
  __shared__ int wt[16];
  if (lane == 63) wt[w] = x;
  __syncthreads();
  int add = 0;
  for (int i = 0; i < w; i++) add += wt[i];
  x += add;
  if (t < n) bsum[t] = x - v;
}

// ---------------- CSR build: scatter ----------------------------------------
// epool record: (src*128, (a0)*128, (64+a1)*128, (128+a2)*128) — element offsets
__global__ void scatter_edges(const int* __restrict__ ei_m, const int* __restrict__ ea_m, int Em,
                              const int* __restrict__ ei_s, const int* __restrict__ ea_s, int Es, int Nm,
                              const int* __restrict__ excl_e, const int* __restrict__ bsum_e,
                              int* __restrict__ cur_e, int4* __restrict__ epool) {
  int i = blockIdx.x * 256 + threadIdx.x;
  int tgt, src, a0, a1, a2;
  if (i < Em) {
    tgt = ei_m[i]; src = ei_m[Em + i];
    a0 = ea_m[i * 3]; a1 = ea_m[i * 3 + 1]; a2 = ea_m[i * 3 + 2];
  } else {
    int j = i - Em; if (j >= Es) return;
    tgt = Nm + ei_s[j]; src = ei_s[Es + j];
    a0 = ea_s[j * 3]; a1 = ea_s[j * 3 + 1]; a2 = ea_s[j * 3 + 2];
  }
  int slot = excl_e[tgt] + bsum_e[tgt >> 8] + atomicAdd(&cur_e[tgt], 1);
  epool[slot] = make_int4(src * 128, a0 * 128, (64 + a1) * 128, (128 + a2) * 128);
}

__global__ void scatter_nodes(const int* __restrict__ bm, int Nm,
                              const int* __restrict__ bs, int Ns, int M,
                              const int* __restrict__ excl_n, const int* __restrict__ bsum_n,
                              int* __restrict__ cur_n, int* __restrict__ npool) {
  int i = blockIdx.x * 256 + threadIdx.x;
  int g, node;
  if (i < Nm) { g = bm[i]; node = i; }
  else { int j = i - Nm; if (j >= Ns) return; g = M + bs[j]; node = j; }
  int slot = excl_n[g] + bsum_n[g >> 8] + atomicAdd(&cur_n[g], 1);
  npool[slot] = node;
}

// ---------------- node embedding --------------------------------------------
__global__ void embed_nodes(const int* __restrict__ x, const float* __restrict__ table,
                            float* __restrict__ h, int N) {
  int i = blockIdx.x * 256 + threadIdx.x;
  if (i >= N * 128) return;
  int n = i >> 7, c = i & 127;
  float s = 0.f;
#pragma unroll
  for (int f = 0; f < 9; f++) {
    int v = x[n * 9 + f];
    s += table[(f * 64 + v) * 128 + c];
  }
  h[i] = s;
}

// ---------------- fused GIN layer -------------------------------------------
// z = (1+eps)*h_in + sum_e relu(h_in[src]+bond(attr))   [CSR gather, no atomics]
// h_out = bn2(relu(bn1(z@w1+b1))@w2+b2) (+relu)         [bf16 MFMA]
__global__ __launch_bounds__(256) void gin_fused(
    const float* __restrict__ hin, float* __restrict__ hout,
    const float* __restrict__ eps_p, const float* __restrict__ bt,
    const int4* __restrict__ epool, const int* __restrict__ excl_e,
    const int* __restrict__ bsum_e, const int* __restrict__ deg_e, int nodebase,
    const unsigned short* __restrict__ w1t, const float* __restrict__ b1,
    const float* __restrict__ g1, const float* __restrict__ be1,
    const unsigned short* __restrict__ w2t, const float* __restrict__ b2,
    const float* __restrict__ g2, const float* __restrict__ be2,
    int N, int do_relu) {
  __shared__ unsigned short zs[64][136];    // 64x128 bf16, +8 pad
  __shared__ unsigned short z1s[64][264];   // 64x256 bf16, +8 pad
  int t = threadIdx.x;
  int r0 = blockIdx.x * 64;
  float eps1 = 1.0f + *eps_p;
  // Phase A: z tile via CSR gather -> bf16 LDS
  {
    int r = t >> 2, cb = (t & 3) << 5;      // 4 threads/row, 32 ch each
    int n = r0 + r;
    if (n < N) {
      float4 A[8];
#pragma unroll
      for (int j = 0; j < 8; j++) A[j] = make_float4(0.f, 0.f, 0.f, 0.f);
      int g = nodebase + n;
      int st = excl_e[g] + bsum_e[g >> 8];
      int de = deg_e[g];
      for (int e = 0; e < de; e++) {
        int4 rec = epool[st + e];
        const float* hs = hin + rec.x;
        const float* p0 = bt + rec.y;
        const float* p1 = bt + rec.z;
        const float* p2 = bt + rec.w;
#pragma unroll
        for (int j = 0; j < 8; j++) {
          int c = cb + j * 4;
          float4 hv = *(const float4*)(hs + c);
          float4 b0 = *(const float4*)(p0 + c);
          float4 b1v = *(const float4*)(p1 + c);
          float4 b2v = *(const float4*)(p2 + c);
          A[j].x += fmaxf(hv.x + b0.x + b1v.x + b2v.x, 0.f);
          A[j].y += fmaxf(hv.y + b0.y + b1v.y + b2v.y, 0.f);
          A[j].z += fmaxf(hv.z + b0.z + b1v.z + b2v.z, 0.f);
          A[j].w += fmaxf(hv.w + b0.w + b1v.w + b2v.w, 0.f);
        }
      }
#pragma unroll
      for (int j = 0; j < 8; j++) {
        int c = cb + j * 4;
        float4 hv = *(const float4*)(hin + (size_t)n * 128 + c);
        us4 o;
        o.x = f2bf(fmaf(eps1, hv.x, A[j].x));
        o.y = f2bf(fmaf(eps1, hv.y, A[j].y));
        o.z = f2bf(fmaf(eps1, hv.z, A[j].z));
        o.w = f2bf(fmaf(eps1, hv.w, A[j].w));
        *(us4*)&zs[r][c] = o;
      }
    } else {
      us4 z4; z4.x = z4.y = z4.z = z4.w = 0;
#pragma unroll
      for (int j = 0; j < 8; j++) *(us4*)&zs[r][cb + j * 4] = z4;
    }
  }
  __syncthreads();
  int lane = t & 63, wave = t >> 6;
  int quad = lane >> 4, l16 = lane & 15;
  // Phase B: z1[64x256] = relu(bn1(z @ w1 + b1)); wave handles 64 cols
  {
    short8 bw[4][4];
    int cb = wave * 64;
#pragma unroll
    for (int nt = 0; nt < 4; nt++) {
      const unsigned short* p = w1t + (cb + nt * 16 + l16) * 128 + quad * 8;
#pragma unroll
      for (int kc = 0; kc < 4; kc++) bw[nt][kc] = *(const short8*)(p + kc * 32);
    }
#pragma unroll
    for (int mt = 0; mt < 4; mt++) {
      short8 af[4];
#pragma unroll
      for (int kc = 0; kc < 4; kc++)
        af[kc] = *(const short8*)&zs[mt * 16 + l16][kc * 32 + quad * 8];
#pragma unroll
      for (int nt = 0; nt < 4; nt++) {
        f32x4 acc = {0.f, 0.f, 0.f, 0.f};
#pragma unroll
        for (int kc = 0; kc < 4; kc++)
          acc = __builtin_amdgcn_mfma_f32_16x16x32_bf16(af[kc], bw[nt][kc], acc, 0, 0, 0);
        int c = cb + nt * 16 + l16;
        float sc = g1[c] * BN_RSQ, sh = be1[c], bb = b1[c];
#pragma unroll
        for (int reg = 0; reg < 4; reg++) {
          int r = mt * 16 + quad * 4 + reg;
          float y = (acc[reg] + bb) * sc + sh;
          z1s[r][c] = f2bf(fmaxf(y, 0.f));
        }
      }
    }
  }
  __syncthreads();
  // Phase C: h_out = bn2(z1 @ w2 + b2) (+relu); wave handles 32 cols
  {
    short8 bw[2][8];
    int cb = wave * 32;
#pragma unroll
    for (int nt = 0; nt < 2; nt++) {
      const unsigned short* p = w2t + (cb + nt * 16 + l16) * 256 + quad * 8;
#pragma unroll
      for (int kc = 0; kc < 8; kc++) bw[nt][kc] = *(const short8*)(p + kc * 32);
    }
#pragma unroll
    for (int mt = 0; mt < 4; mt++) {
      short8 af[8];
#pragma unroll
      for (int kc = 0; kc < 8; kc++)
        af[kc] = *(const short8*)&z1s[mt * 16 + l16][kc * 32 + quad * 8];
#pragma unroll
      for (int nt = 0; nt < 2; nt++) {
        f32x4 acc = {0.f, 0.f, 0.f, 0.f};
#pragma unroll
        for (int kc = 0; kc < 8; kc++)
          acc = __builtin_amdgcn_mfma_f32_16x16x32_bf16(af[kc], bw[nt][kc], acc, 0, 0, 0);
        int c = cb + nt * 16 + l16;
        float sc = g2[c] * BN_RSQ, sh = be2[c], bb = b2[c];
#pragma unroll
        for (int reg = 0; reg < 4; reg++) {
          int n = r0 + mt * 16 + quad * 4 + reg;
          if (n < N) {
            float y = (acc[reg] + bb) * sc + sh;
            if (do_relu) y = fmaxf(y, 0.f);
            hout[n * 128 + c] = y;
          }
        }
      }
    }
  }
}

// ---------------- CSR mean pooling ------------------------------------------
__global__ __launch_bounds__(128) void pool_csr(const float* __restrict__ h,
                                                const int* __restrict__ npool,
                                                const int* __restrict__ excl_n,
                                                const int* __restrict__ bsum_n,
                                                const int* __restrict__ deg_n,
                                                int segbase, float* __restrict__ pooled, int nseg) {
  int m = blockIdx.x;
  if (m >= nseg) return;
  int g = segbase + m;
  int st = excl_n[g] + bsum_n[g >> 8];
  int len = deg_n[g];
  int c = threadIdx.x;
  float s = 0.f;
  int e = st + len, i = st;
  for (; i + 3 < e; i += 4) {
    int n0 = npool[i], n1 = npool[i + 1], n2 = npool[i + 2], n3 = npool[i + 3];
    float v0 = h[(size_t)n0 * 128 + c];
    float v1 = h[(size_t)n1 * 128 + c];
    float v2 = h[(size_t)n2 * 128 + c];
    float v3 = h[(size_t)n3 * 128 + c];
    s += (v0 + v1) + (v2 + v3);
  }
  for (; i < e; i++) s += h[(size_t)npool[i] * 128 + c];
  pooled[m * 128 + c] = s / ((float)len + 1e-9f);
}

// ---------------- small generic GEMM: C = A[MxK] @ W[KxN] + bias -----------
__global__ void gemm_small(const float* __restrict__ A, const float* __restrict__ W,
                           const float* __restrict__ bias, float* __restrict__ C,
                           int M, int N, int K) {
  int i = blockIdx.x * 256 + threadIdx.x;
  if (i >= M * N) return;
  int r = i / N, c = i - r * N;
  float acc = bias ? bias[c] : 0.f;
  const float* a = A + (size_t)r * K;
  for (int k = 0; k < K; k++) acc = fmaf(a[k], W[(size_t)k * N + c], acc);
  C[i] = acc;
}

// ---------------- SAB attention: O = Qs + softmax(QsKs^T/8) Vs -------------
__global__ __launch_bounds__(256) void sab_attn(const float* __restrict__ Q, const float* __restrict__ K,
                                                const float* __restrict__ V, float* __restrict__ O, int S) {
  int q = blockIdx.x, hd = blockIdx.y;
  int t = threadIdx.x;
  __shared__ float sc[512];
  __shared__ float red[8];
  __shared__ float pacc[4][64];
  const float* qrow = Q + q * 128 + hd * 64;
  for (int k = t; k < 512; k += 256) {
    float d = -1e30f;
    if (k < S) {
      const float* krow = K + k * 128 + hd * 64;
      d = 0.f;
#pragma unroll
      for (int j = 0; j < 64; j += 4) {
        float4 a = *(const float4*)(qrow + j);
        float4 b = *(const float4*)(krow + j);
        d += a.x * b.x + a.y * b.y + a.z * b.z + a.w * b.w;
      }
      d *= 0.125f;
    }
    sc[k] = d;
  }
  __syncthreads();
  float m = fmaxf(sc[t], sc[t + 256]);
  for (int off = 32; off; off >>= 1) m = fmaxf(m, __shfl_down(m, off));
  if ((t & 63) == 0) red[t >> 6] = m;
  __syncthreads();
  m = fmaxf(fmaxf(red[0], red[1]), fmaxf(red[2], red[3]));
  float p0 = __expf(sc[t] - m), p1 = __expf(sc[t + 256] - m);
  sc[t] = p0; sc[t + 256] = p1;
  float s = p0 + p1;
  for (int off = 32; off; off >>= 1) s += __shfl_down(s, off);
  if ((t & 63) == 0) red[4 + (t >> 6)] = s;
  __syncthreads();
  float inv = 1.f / (red[4] + red[5] + red[6] + red[7]);
  int d = t & 63, part = t >> 6;
  float acc = 0.f;
  for (int k = part; k < S; k += 4) acc += sc[k] * V[k * 128 + hd * 64 + d];
  pacc[part][d] = acc;
  __syncthreads();
  if (part == 0) {
    float o = (pacc[0][d] + pacc[1][d] + pacc[2][d] + pacc[3][d]) * inv;
    O[q * 128 + hd * 64 + d] = qrow[d] + o;
  }
}

// ---------------- row LayerNorm over 128 ------------------------------------
__global__ __launch_bounds__(128) void ln_rows(const float* __restrict__ in, float* __restrict__ out,
                                               const float* __restrict__ g, const float* __restrict__ b) {
  int r = blockIdx.x, t = threadIdx.x;
  __shared__ float red[4];
  float x = in[r * 128 + t];
  float s = x;
  for (int off = 32; off; off >>= 1) s += __shfl_down(s, off);
  if ((t & 63) == 0) red[t >> 6] = s;
  __syncthreads();
  float mu = (red[0] + red[1]) * (1.f / 128.f);
  float dd = x - mu;
  float v = dd * dd;
  for (int off = 32; off; off >>= 1) v += __shfl_down(v, off);
  if ((t & 63) == 0) red[2 + (t >> 6)] = v;
  __syncthreads();
  float var = (red[2] + red[3]) * (1.f / 128.f);
  out[r * 128 + t] = g[t] * dd * rsqrtf(var + LN_EPS) + b[t];
}

// ---------------- masked softmax attn: attn[d,s] ----------------------------
__global__ __launch_bounds__(256) void agg_attn(const float* __restrict__ Q, const float* __restrict__ Kt,
                                                const void* __restrict__ mask, const int* __restrict__ flags,
                                                float* __restrict__ attn, int D, int S) {
  int d = blockIdx.x, t = threadIdx.x;
  __shared__ float sc[512];
  __shared__ float red[8];
  int layout = (flags[1] == 0) ? 0 : (flags[0] ? 1 : 2);
  const float* qrow = Q + d * 128;
  for (int s = t; s < 512; s += 256) {
    float v = NEGBIG;
    if (s < S) {
      int mi = d * S + s;
      bool msk;
      if (layout == 0)      msk = ((const int*)mask)[mi] != 0;
      else if (layout == 1) msk = ((const unsigned char*)mask)[mi] != 0;
      else                  msk = ((const float*)mask)[mi] != 0.f;
      if (!msk) {
        float dd = 0.f;
        const float* krow = Kt + s * 128;
#pragma unroll
        for (int j = 0; j < 128; j += 4) {
          float4 a = *(const float4*)(qrow + j);
          float4 b = *(const float4*)(krow + j);
          dd += a.x * b.x + a.y * b.y + a.z * b.z + a.w * b.w;
        }
        v = dd * 0.08838834764831845f;
      }
    }
    sc[s] = v;
  }
  __syncthreads();
  float m = fmaxf(sc[t], sc[t + 256]);
  for (int off = 32; off; off >>= 1) m = fmaxf(m, __shfl_down(m, off));
  if ((t & 63) == 0) red[t >> 6] = m;
  __syncthreads();
  m = fmaxf(fmaxf(red[0], red[1]), fmaxf(red[2], red[3]));
  float p0 = __expf(sc[t] - m), p1 = __expf(sc[t + 256] - m);
  float s2 = p0 + p1;
  for (int off = 32; off; off >>= 1) s2 += __shfl_down(s2, off);
  if ((t & 63) == 0) red[4 + (t >> 6)] = s2;
  __syncthreads();
  float inv = 1.f / (red[4] + red[5] + red[6] + red[7]);
  attn[d * S + t] = p0 * inv;
  if (t + 256 < S) attn[d * S + t + 256] = p1 * inv;
}

// ---------------- subT prep: subf [S][128] f32 -> subT bf16 [128][512] ------
__global__ void prep_subT(const float* __restrict__ subf, unsigned short* __restrict__ subT, int S) {
  int i = blockIdx.x * 256 + threadIdx.x;
  if (i >= 128 * 512) return;
  int hh = i >> 9, k = i & 511;
  subT[i] = (k < S) ? f2bf(subf[k * 128 + hh]) : (unsigned short)0;
}

// ---------------- agg via MFMA: per d, (pat .* attn[d])[64x492] @ sub -------
__global__ __launch_bounds__(256) void agg_mfma(const float* __restrict__ attn, const float* __restrict__ pat,
                                                const unsigned short* __restrict__ subT,
                                                float* __restrict__ aggT, int D, int S) {
  int d = blockIdx.x, t = threadIdx.x;
  __shared__ unsigned short As[64][40];
  int lane = t & 63, wave = t >> 6;
  int quad = lane >> 4, l16 = lane & 15;
  f32x4 acc[8];
#pragma unroll
  for (int nt = 0; nt < 8; nt++) acc[nt] = (f32x4){0.f, 0.f, 0.f, 0.f};
  const float* arow = attn + d * S;
  int srow = t >> 2, skb = (t & 3) * 8;
  for (int c = 0; c < 16; c++) {
    int s0 = c * 32;
    __syncthreads();
    unsigned short v[8];
#pragma unroll
    for (int j = 0; j < 8; j++) {
      int s = s0 + skb + j;
      float x = (s < S) ? arow[s] * pat[srow * S + s] : 0.f;
      v[j] = f2bf(x);
    }
    *(us4*)&As[srow][skb]     = *(us4*)&v[0];
    *(us4*)&As[srow][skb + 4] = *(us4*)&v[4];
    __syncthreads();
    short8 af = *(const short8*)&As[16 * wave + l16][quad * 8];
#pragma unroll
    for (int nt = 0; nt < 8; nt++) {
      short8 bf = *(const short8*)(subT + (nt * 16 + l16) * 512 + s0 + quad * 8);
      acc[nt] = __builtin_amdgcn_mfma_f32_16x16x32_bf16(af, bf, acc[nt], 0, 0, 0);
    }
  }
#pragma unroll
  for (int nt = 0; nt < 8; nt++) {
    int hh = nt * 16 + l16;
#pragma unroll
    for (int reg = 0; reg < 4; reg++) {
      int b = 16 * wave + quad * 4 + reg;
      aggT[((size_t)(b * D + d)) * 128 + hh] = acc[nt][reg];
    }
  }
}

// ---------------- score head: sigmoid(relu(agg@w1+b1)@w2+b2) ---------------
__global__ __launch_bounds__(64) void score_head(const float* __restrict__ aggT,
                                                 const float* __restrict__ w1, const float* __restrict__ b1,
                                                 const float* __restrict__ w2, const float* __restrict__ b2,
                                                 float* __restrict__ out) {
  int i = blockIdx.x;
  int j = threadIdx.x;
  const float* av = aggT + (size_t)i * 128;
  float acc = b1[j];
#pragma unroll 8
  for (int k = 0; k < 128; k++) acc = fmaf(av[k], w1[k * 64 + j], acc);
  acc = fmaxf(acc, 0.f) * w2[j];
  for (int off = 32; off; off >>= 1) acc += __shfl_down(acc, off);
  if (j == 0) {
    float x = acc + b2[0];
    out[i] = 1.f / (1.f + __expf(-x));
  }
}

// ---------------------------------------------------------------------------
extern "C" void kernel_launch(void* const* d_in, const int* in_sizes, int n_in,
                              void* d_out, int out_size, void* d_ws, size_t ws_size,
                              hipStream_t stream) {
  const float* atom_emb = (const float*)d_in[0];
  const float* bond_emb = (const float*)d_in[1];
  const float* gin_eps  = (const float*)d_in[2];
  const float* gin_w1   = (const float*)d_in[3];
  const float* gin_b1   = (const float*)d_in[4];
  const float* bn1g     = (const float*)d_in[5];
  const float* bn1b     = (const float*)d_in[6];
  const float* gin_w2   = (const float*)d_in[7];
  const float* gin_b2   = (const float*)d_in[8];
  const float* bn2g     = (const float*)d_in[9];
  const float* bn2b     = (const float*)d_in[10];
  const float* sab_wq = (const float*)d_in[11];
  const float* sab_wk = (const float*)d_in[12];
  const float* sab_wv = (const float*)d_in[13];
  const float* sab_wo = (const float*)d_in[14];
  const float* sab_bq = (const float*)d_in[15];
  const float* sab_bk = (const float*)d_in[16];
  const float* sab_bv = (const float*)d_in[17];
  const float* sab_bo = (const float*)d_in[18];
  const float* ln1b = (const float*)d_in[19];
  const float* ln2b = (const float*)d_in[20];
  const float* ln1g = (const float*)d_in[21];
  const float* ln2g = (const float*)d_in[22];
  const float* agg_wq = (const float*)d_in[23];
  const float* agg_bq = (const float*)d_in[24];
  const float* agg_wk = (const float*)d_in[25];
  const float* agg_bk = (const float*)d_in[26];
  const float* score_w1 = (const float*)d_in[27];
  const float* score_b1 = (const float*)d_in[28];
  const float* score_w2 = (const float*)d_in[29];
  const float* score_b2 = (const float*)d_in[30];
  const float* patient  = (const float*)d_in[31];
  const float* avgproj  = (const float*)d_in[32];
  const int* sub_x     = (const int*)d_in[33];
  const int* sub_ea    = (const int*)d_in[34];
  const int* sub_ei    = (const int*)d_in[35];
  const int* sub_batch = (const int*)d_in[36];
  const int* mol_x     = (const int*)d_in[37];
  const int* mol_ea    = (const int*)d_in[38];
  const int* mol_ei    = (const int*)d_in[39];
  const int* mol_batch = (const int*)d_in[40];
  const void* mask     = d_in[41];

  const int Ns = in_sizes[33] / 9, Es = in_sizes[34] / 3;
  const int Nm = in_sizes[37] / 9, Em = in_sizes[38] / 3;
  const int S = 492, M = 600, D = 200, B = 64;
  const int NE = Nm + Ns;           // edge-CSR index space (mol first)
  const int NSEG = M + S;           // node-CSR index space (mol first)
  const int ETOT = Em + Es;

  // ---- workspace carve-up ----
  char* Wp = (char*)d_ws;
  size_t off = 0;
  auto alloc = [&](size_t bytes) -> void* {
    void* p = Wp + off;
    off = (off + bytes + 255) & ~(size_t)255;
    return p;
  };
  int NR = ((Nm > Ns ? Nm : Ns) + 63) & ~63;
  float* h0 = (float*)alloc((size_t)NR * 128 * 4);
  float* h1 = (float*)alloc((size_t)NR * 128 * 4);
  unsigned short* w1t = (unsigned short*)alloc(262144 * 2);
  unsigned short* w2t = (unsigned short*)alloc(262144 * 2);
  int4* epool  = (int4*)alloc((size_t)ETOT * 16);
  int*  npool  = (int*)alloc((size_t)NE * 4);
  int*  excl_e = (int*)alloc((size_t)NE * 4);
  int*  bsum_e = (int*)alloc(1024 * 4);
  int*  excl_n = (int*)alloc((size_t)NSEG * 4);
  int*  bsum_n = (int*)alloc(1024 * 4);
  char* zstart = Wp + off;                       // region zeroed below
  int*  deg_e  = (int*)alloc((size_t)NE * 4);
  int*  deg_n  = (int*)alloc((size_t)NSEG * 4);
  int*  cur_e  = (int*)alloc((size_t)NE * 4);
  int*  cur_n  = (int*)alloc((size_t)NSEG * 4);
  int*  flags  = (int*)alloc(8);
  size_t zsize = (size_t)((Wp + off) - zstart);
  float* pooled_sub = (float*)alloc((size_t)S * 128 * 4);
  float* pooled_mol = (float*)alloc((size_t)M * 128 * 4);
  float* Qb   = (float*)alloc((size_t)S * 128 * 4);
  float* Kb   = (float*)alloc((size_t)S * 128 * 4);
  float* Vb   = (float*)alloc((size_t)S * 128 * 4);
  float* Ob   = (float*)alloc((size_t)S * 128 * 4);
  float* O2b  = (float*)alloc((size_t)S * 128 * 4);
  float* subf = (float*)alloc((size_t)S * 128 * 4);
  unsigned short* subT = (unsigned short*)alloc((size_t)128 * 512 * 2);
  float* mol_embb = (float*)alloc((size_t)D * 128 * 4);
  float* aggQb = (float*)alloc((size_t)D * 128 * 4);
  float* aggKb = (float*)alloc((size_t)S * 128 * 4);
  float* attnb = (float*)alloc((size_t)D * S * 4);
  float* aggTb = (float*)alloc((size_t)B * D * 128 * 4);
  (void)ws_size; (void)n_in; (void)out_size;

  hipMemsetAsync(zstart, 0, zsize, stream);
  prep_weights<<<1024, 256, 0, stream>>>(gin_w1, gin_w2, w1t, w2t);
  mask_detect<<<(D * S + 255) / 256, 256, 0, stream>>>((const unsigned char*)mask, flags, D * S);

  // ---- CSR build (edges by tgt; nodes by batch) ----
  int total_cnt = Em + Es + Nm + Ns;
  build_count<<<(total_cnt + 255) / 256, 256, 0, stream>>>(
      mol_ei, Em, sub_ei, Es, mol_batch, Nm, sub_batch, Ns, deg_e, deg_n, M);
  int nb_e = (NE + 255) / 256;        // <= 1024
  int nb_n = (NSEG + 255) / 256;
  scan_block<<<nb_e, 256, 0, stream>>>(deg_e, NE, excl_e, bsum_e);
  scan_top<<<1, 1024, 0, stream>>>(bsum_e, nb_e);
  scan_block<<<nb_n, 256, 0, stream>>>(deg_n, NSEG, excl_n, bsum_n);
  scan_top<<<1, 1024, 0, stream>>>(bsum_n, nb_n);
  scatter_edges<<<(ETOT + 255) / 256, 256, 0, stream>>>(
      mol_ei, mol_ea, Em, sub_ei, sub_ea, Es, Nm, excl_e, bsum_e, cur_e, epool);
  scatter_nodes<<<(NE + 255) / 256, 256, 0, stream>>>(
      mol_batch, Nm, sub_batch, Ns, M, excl_n, bsum_n, cur_n, npool);

  auto run_gin = [&](int g, int N, const int* x, int nodebase, int segbase,
                     float* pooled, int nseg) {
    embed_nodes<<<(N * 128 + 255) / 256, 256, 0, stream>>>(
        x, atom_emb + (size_t)g * 9 * 64 * 128, h0, N);
    float* hin = h0; float* hout = h1;
    for (int l = 0; l < 4; l++) {
      int gl = g * 4 + l;
      gin_fused<<<(N + 63) / 64, 256, 0, stream>>>(
          hin, hout, gin_eps + gl, bond_emb + (size_t)gl * 3 * 64 * 128,
          epool, excl_e, bsum_e, deg_e, nodebase,
          w1t + (size_t)gl * 32768, gin_b1 + gl * 256, bn1g + gl * 256, bn1b + gl * 256,
          w2t + (size_t)gl * 32768, gin_b2 + gl * 128, bn2g + gl * 128, bn2b + gl * 128,
          N, (l != 3) ? 1 : 0);
      float* tmp = hin; hin = hout; hout = tmp;
    }
    // after 4 layers final h is back in h0 (hin)
    pool_csr<<<nseg, 128, 0, stream>>>(hin, npool, excl_n, bsum_n, deg_n, segbase, pooled, nseg);
  };

  // --- substructure encoder + SAB ---
  run_gin(0, Ns, sub_x, Nm, M, pooled_sub, S);
  gemm_small<<<(S * 128 + 255) / 256, 256, 0, stream>>>(pooled_sub, sab_wq, sab_bq, Qb, S, 128, 128);
  gemm_small<<<(S * 128 + 255) / 256, 256, 0, stream>>>(pooled_sub, sab_wk, sab_bk, Kb, S, 128, 128);
  gemm_small<<<(S * 128 + 255) / 256, 256, 0, stream>>>(pooled_sub, sab_wv, sab_bv, Vb, S, 128, 128);
  sab_attn<<<dim3(S, 2), 256, 0, stream>>>(Qb, Kb, Vb, Ob, S);
  ln_rows<<<S, 128, 0, stream>>>(Ob, Ob, ln1g, ln1b);
  gemm_small<<<(S * 128 + 255) / 256, 256, 0, stream>>>(Ob, sab_wo, sab_bo, O2b, S, 128, 128);
  ln_rows<<<S, 128, 0, stream>>>(O2b, subf, ln2g, ln2b);
  prep_subT<<<(128 * 512 + 255) / 256, 256, 0, stream>>>(subf, subT, S);

  // --- molecule encoder + projection ---
  run_gin(1, Nm, mol_x, 0, 0, pooled_mol, M);
  gemm_small<<<(D * 128 + 255) / 256, 256, 0, stream>>>(avgproj, pooled_mol, (const float*)nullptr, mol_embb, D, 128, M);

  // --- attention aggregation + score ---
  gemm_small<<<(D * 128 + 255) / 256, 256, 0, stream>>>(mol_embb, agg_wq, agg_bq, aggQb, D, 128, 128);
  gemm_small<<<(S * 128 + 255) / 256, 256, 0, stream>>>(subf, agg_wk, agg_bk, aggKb, S, 128, 128);
  agg_attn<<<D, 256, 0, stream>>>(aggQb, aggKb, mask, flags, attnb, D, S);
  agg_mfma<<<D, 256, 0, stream>>>(attnb, patient, subT, aggTb, D, S);
  score_head<<<B * D, 64, 0, stream>>>(aggTb, score_w1, score_b1, score_w2, score_b2, (float*)d_out);
}